// Round 2
// baseline (420.007 us; speedup 1.0000x reference)
//
#include <hip/hip_runtime.h>
#include <stdint.h>

typedef int int32x4 __attribute__((ext_vector_type(4)));

#define IN_F   4096
#define OUT_F  4096
#define ROWS   8192   /* 4 * 2048 */

#define BM 128
#define BN 128
#define BK 64

// async global->LDS, 16B per lane; LDS side must be lane-contiguous (m104/m108)
#define GLOAD_LDS16(g, l)                                                      \
  __builtin_amdgcn_global_load_lds(                                            \
      (const __attribute__((address_space(1))) void*)(g),                      \
      (__attribute__((address_space(3))) void*)(l), 16, 0, 0)

__device__ __forceinline__ int pack4i(int a, int b, int c, int d) {
  return (a & 0xff) | ((b & 0xff) << 8) | ((c & 0xff) << 16) | (d << 24);
}

// ---- int32 -> int8 (x): one thread per 16 elements --------------------------
__global__ void __launch_bounds__(256) cvt_x_kernel(const int* __restrict__ x,
                                                    int8_t* __restrict__ o) {
  size_t i = (size_t)blockIdx.x * 256 + threadIdx.x;
  const int4* xp = (const int4*)x + i * 4;
  int4 a = xp[0], b = xp[1], c = xp[2], d = xp[3];
  int4 r;
  r.x = pack4i(a.x, a.y, a.z, a.w);
  r.y = pack4i(b.x, b.y, b.z, b.w);
  r.z = pack4i(c.x, c.y, c.z, c.w);
  r.w = pack4i(d.x, d.y, d.z, d.w);
  ((int4*)o)[i] = r;
}

// ---- fp32 -> int8 (weight): one thread per 16 elements ----------------------
__global__ void __launch_bounds__(256) cvt_w_kernel(const float* __restrict__ w,
                                                    int8_t* __restrict__ o) {
  size_t i = (size_t)blockIdx.x * 256 + threadIdx.x;
  const float4* wp = (const float4*)w + i * 4;
  float4 a = wp[0], b = wp[1], c = wp[2], d = wp[3];
  int4 r;
  r.x = pack4i(__float2int_rn(a.x), __float2int_rn(a.y), __float2int_rn(a.z), __float2int_rn(a.w));
  r.y = pack4i(__float2int_rn(b.x), __float2int_rn(b.y), __float2int_rn(b.z), __float2int_rn(b.w));
  r.z = pack4i(__float2int_rn(c.x), __float2int_rn(c.y), __float2int_rn(c.z), __float2int_rn(c.w));
  r.w = pack4i(__float2int_rn(d.x), __float2int_rn(d.y), __float2int_rn(d.z), __float2int_rn(d.w));
  ((int4*)o)[i] = r;
}

// ---- i8 MFMA GEMM: C[m,n] = sum_k A[m,k]*B[n,k]  (both row-major [rows][K]) -
// block tile 128x128, BK=64; 4 waves in 2x2, each wave 64x64 via 4x4 tiles of
// mfma_i32_16x16x64_i8.  Epilogue: clamp(rint(acc*alpha + bias)) as int32.
__global__ void __launch_bounds__(256) gemm_i8_kernel(
    const int8_t* __restrict__ A8, const int8_t* __restrict__ B8,
    const float* __restrict__ bias, const float* __restrict__ alpha_p,
    int* __restrict__ out) {
  __shared__ int8_t As[BM * BK];  // 8 KB, row-major [128][64]
  __shared__ int8_t Bs[BN * BK];  // 8 KB

  const int t = threadIdx.x;
  const int wave = t >> 6;
  const int lane = t & 63;
  const int quad = lane >> 4;   // 0..3
  const int l15 = lane & 15;
  const int wm = wave >> 1;     // 0..1
  const int wn = wave & 1;      // 0..1

  const int bn = blockIdx.x;    // 0..31
  const int bm = blockIdx.y;    // 0..63

  // staging: 512 chunks of 16B per tile; thread t owns chunks t and t+256.
  const int rowS = t >> 2;               // 0..63
  const int colS = (t & 3) * 16;
  const int8_t* ag0 = A8 + (size_t)(bm * BM + rowS) * IN_F + colS;
  const int8_t* ag1 = ag0 + (size_t)64 * IN_F;
  const int8_t* bg0 = B8 + (size_t)(bn * BN + rowS) * IN_F + colS;
  const int8_t* bg1 = bg0 + (size_t)64 * IN_F;
  int8_t* la0 = As + t * 16;
  int8_t* la1 = As + t * 16 + 4096;
  int8_t* lb0 = Bs + t * 16;
  int8_t* lb1 = Bs + t * 16 + 4096;

  // fragment read offsets in 16B units: row*(64/16) + quad
  const int32x4* As4 = (const int32x4*)As;
  const int32x4* Bs4 = (const int32x4*)Bs;
  const int aoff = (wm * 64 + l15) * 4 + quad;
  const int boff = (wn * 64 + l15) * 4 + quad;

  int32x4 acc[4][4] = {};

  for (int k0 = 0; k0 < IN_F; k0 += BK) {
    GLOAD_LDS16(ag0 + k0, la0);
    GLOAD_LDS16(ag1 + k0, la1);
    GLOAD_LDS16(bg0 + k0, lb0);
    GLOAD_LDS16(bg1 + k0, lb1);
    __syncthreads();

    int32x4 af[4], bf[4];
#pragma unroll
    for (int i = 0; i < 4; ++i) af[i] = As4[aoff + i * 64];  // +16 rows
#pragma unroll
    for (int i = 0; i < 4; ++i) bf[i] = Bs4[boff + i * 64];
#pragma unroll
    for (int mi = 0; mi < 4; ++mi)
#pragma unroll
      for (int ni = 0; ni < 4; ++ni)
        acc[mi][ni] = __builtin_amdgcn_mfma_i32_16x16x64_i8(af[mi], bf[ni],
                                                            acc[mi][ni], 0, 0, 0);
    __syncthreads();
  }

  // epilogue: C/D layout col = lane&15, row = quad*4 + reg (dtype-independent)
  const float alpha = *alpha_p;
  const int colg = bn * BN + wn * 64 + l15;
  const int rowg = bm * BM + wm * 64 + quad * 4;
#pragma unroll
  for (int mi = 0; mi < 4; ++mi) {
#pragma unroll
    for (int ni = 0; ni < 4; ++ni) {
      const int col = colg + ni * 16;
      const float bv = bias[col];
#pragma unroll
      for (int r = 0; r < 4; ++r) {
        const int row = rowg + mi * 16 + r;
        float v = rintf((float)acc[mi][ni][r] * alpha + bv);
        v = fminf(fmaxf(v, -128.f), 127.f);
        out[(size_t)row * OUT_F + col] = (int)v;
      }
    }
  }
}

extern "C" void kernel_launch(void* const* d_in, const int* in_sizes, int n_in,
                              void* d_out, int out_size, void* d_ws, size_t ws_size,
                              hipStream_t stream) {
  const int*   x     = (const int*)d_in[0];    // [8192, 4096] int8-valued
  const float* w     = (const float*)d_in[1];  // [4096, 4096] int8-valued
  const float* bias  = (const float*)d_in[2];  // [4096]
  const float* alpha = (const float*)d_in[3];  // scalar
  int* out = (int*)d_out;                      // [8192, 4096] int32 (int8 values)

  int8_t* x8 = (int8_t*)d_ws;                        // 33,554,432 B
  int8_t* w8 = x8 + (size_t)ROWS * IN_F;             // 16,777,216 B (total 48 MB)

  // x: 33,554,432 elems / 16 per thread = 2,097,152 threads
  cvt_x_kernel<<<8192, 256, 0, stream>>>(x, x8);
  // w: 16,777,216 elems / 16 per thread = 1,048,576 threads
  cvt_w_kernel<<<4096, 256, 0, stream>>>(w, w8);

  dim3 grid(OUT_F / BN, ROWS / BM);  // (32, 64)
  gemm_i8_kernel<<<grid, 256, 0, stream>>>(x8, w8, bias, alpha, out);
}

// Round 3
// 414.196 us; speedup vs baseline: 1.0140x; 1.0140x over previous
//
#include <hip/hip_runtime.h>
#include <stdint.h>

typedef int int32x4 __attribute__((ext_vector_type(4)));

#define IN_F   4096
#define OUT_F  4096
#define ROWS   8192   /* 4 * 2048 */

#define BM 128
#define BN 128
#define BK 64

// async global->LDS, 16B per lane; LDS side must be lane-contiguous (m104/m108)
#define GLOAD_LDS16(g, l)                                                      \
  __builtin_amdgcn_global_load_lds(                                            \
      (const __attribute__((address_space(1))) void*)(g),                      \
      (__attribute__((address_space(3))) void*)(l), 16, 0, 0)

__device__ __forceinline__ int pack4i(int a, int b, int c, int d) {
  return (a & 0xff) | ((b & 0xff) << 8) | ((c & 0xff) << 16) | (d << 24);
}

// ---- int32 -> int8 (x): one thread per 4 elements, fully coalesced ----------
// lane reads one int4 (16B, consecutive lanes -> consecutive 16B), writes one
// packed int (4B, consecutive).
__global__ void __launch_bounds__(256) cvt_x_kernel(const int4* __restrict__ x,
                                                    int* __restrict__ o) {
  size_t i = (size_t)blockIdx.x * 256 + threadIdx.x;
  int4 a = x[i];
  o[i] = pack4i(a.x, a.y, a.z, a.w);
}

// ---- fp32 -> int8 (weight): one thread per 4 elements, fully coalesced ------
__global__ void __launch_bounds__(256) cvt_w_kernel(const float4* __restrict__ w,
                                                    int* __restrict__ o) {
  size_t i = (size_t)blockIdx.x * 256 + threadIdx.x;
  float4 a = w[i];
  o[i] = pack4i(__float2int_rn(a.x), __float2int_rn(a.y),
                __float2int_rn(a.z), __float2int_rn(a.w));
}

// ---- i8 MFMA GEMM: C[m,n] = sum_k A[m,k]*B[n,k]  (both row-major [rows][K]) -
// block tile 128x128, BK=64; 4 waves in 2x2, each wave 64x64 via 4x4 tiles of
// mfma_i32_16x16x64_i8.  Epilogue: clamp(rint(acc*alpha + bias)) as int32.
__global__ void __launch_bounds__(256) gemm_i8_kernel(
    const int8_t* __restrict__ A8, const int8_t* __restrict__ B8,
    const float* __restrict__ bias, const float* __restrict__ alpha_p,
    int* __restrict__ out) {
  __shared__ int8_t As[BM * BK];  // 8 KB, row-major [128][64]
  __shared__ int8_t Bs[BN * BK];  // 8 KB

  const int t = threadIdx.x;
  const int wave = t >> 6;
  const int lane = t & 63;
  const int quad = lane >> 4;   // 0..3
  const int l15 = lane & 15;
  const int wm = wave >> 1;     // 0..1
  const int wn = wave & 1;      // 0..1

  const int bn = blockIdx.x;    // 0..31
  const int bm = blockIdx.y;    // 0..63

  // staging: 512 chunks of 16B per tile; thread t owns chunks t and t+256.
  const int rowS = t >> 2;               // 0..63
  const int colS = (t & 3) * 16;
  const int8_t* ag0 = A8 + (size_t)(bm * BM + rowS) * IN_F + colS;
  const int8_t* ag1 = ag0 + (size_t)64 * IN_F;
  const int8_t* bg0 = B8 + (size_t)(bn * BN + rowS) * IN_F + colS;
  const int8_t* bg1 = bg0 + (size_t)64 * IN_F;
  int8_t* la0 = As + t * 16;
  int8_t* la1 = As + t * 16 + 4096;
  int8_t* lb0 = Bs + t * 16;
  int8_t* lb1 = Bs + t * 16 + 4096;

  // fragment read offsets in 16B units: row*(64/16) + quad
  const int32x4* As4 = (const int32x4*)As;
  const int32x4* Bs4 = (const int32x4*)Bs;
  const int aoff = (wm * 64 + l15) * 4 + quad;
  const int boff = (wn * 64 + l15) * 4 + quad;

  int32x4 acc[4][4] = {};

  for (int k0 = 0; k0 < IN_F; k0 += BK) {
    GLOAD_LDS16(ag0 + k0, la0);
    GLOAD_LDS16(ag1 + k0, la1);
    GLOAD_LDS16(bg0 + k0, lb0);
    GLOAD_LDS16(bg1 + k0, lb1);
    __syncthreads();

    int32x4 af[4], bf[4];
#pragma unroll
    for (int i = 0; i < 4; ++i) af[i] = As4[aoff + i * 64];  // +16 rows
#pragma unroll
    for (int i = 0; i < 4; ++i) bf[i] = Bs4[boff + i * 64];
#pragma unroll
    for (int mi = 0; mi < 4; ++mi)
#pragma unroll
      for (int ni = 0; ni < 4; ++ni)
        acc[mi][ni] = __builtin_amdgcn_mfma_i32_16x16x64_i8(af[mi], bf[ni],
                                                            acc[mi][ni], 0, 0, 0);
    __syncthreads();
  }

  // epilogue: C/D layout col = lane&15, row = quad*4 + reg (dtype-independent)
  const float alpha = *alpha_p;
  const int colg = bn * BN + wn * 64 + l15;
  const int rowg = bm * BM + wm * 64 + quad * 4;
#pragma unroll
  for (int mi = 0; mi < 4; ++mi) {
#pragma unroll
    for (int ni = 0; ni < 4; ++ni) {
      const int col = colg + ni * 16;
      const float bv = bias[col];
#pragma unroll
      for (int r = 0; r < 4; ++r) {
        const int row = rowg + mi * 16 + r;
        float v = rintf((float)acc[mi][ni][r] * alpha + bv);
        v = fminf(fmaxf(v, -128.f), 127.f);
        out[(size_t)row * OUT_F + col] = (int)v;
      }
    }
  }
}

extern "C" void kernel_launch(void* const* d_in, const int* in_sizes, int n_in,
                              void* d_out, int out_size, void* d_ws, size_t ws_size,
                              hipStream_t stream) {
  const int*   x     = (const int*)d_in[0];    // [8192, 4096] int8-valued
  const float* w     = (const float*)d_in[1];  // [4096, 4096] int8-valued
  const float* bias  = (const float*)d_in[2];  // [4096]
  const float* alpha = (const float*)d_in[3];  // scalar
  int* out = (int*)d_out;                      // [8192, 4096] int32 (int8 values)

  int8_t* x8 = (int8_t*)d_ws;                        // 33,554,432 B
  int8_t* w8 = x8 + (size_t)ROWS * IN_F;             // 16,777,216 B (total 48 MB)

  // x: 33,554,432 elems / 4 per thread = 8,388,608 threads = 32768 blocks
  cvt_x_kernel<<<32768, 256, 0, stream>>>((const int4*)x, (int*)x8);
  // w: 16,777,216 elems / 4 per thread = 4,194,304 threads = 16384 blocks
  cvt_w_kernel<<<16384, 256, 0, stream>>>((const float4*)w, (int*)w8);

  dim3 grid(OUT_F / BN, ROWS / BM);  // (32, 64)
  gemm_i8_kernel<<<grid, 256, 0, stream>>>(x8, w8, bias, alpha, out);
}

// Round 4
// 411.800 us; speedup vs baseline: 1.0199x; 1.0058x over previous
//
#include <hip/hip_runtime.h>
#include <stdint.h>

typedef int int32x4 __attribute__((ext_vector_type(4)));

#define IN_F   4096
#define OUT_F  4096
#define ROWS   8192   /* 4 * 2048 */

#define BM 128
#define BN 128
#define BK 64

// async global->LDS, 16B per lane; LDS side must be lane-contiguous (m104/m108)
#define GLOAD_LDS16(g, l)                                                      \
  __builtin_amdgcn_global_load_lds(                                            \
      (const __attribute__((address_space(1))) void*)(g),                      \
      (__attribute__((address_space(3))) void*)(l), 16, 0, 0)

__device__ __forceinline__ int pack4i(int a, int b, int c, int d) {
  return (a & 0xff) | ((b & 0xff) << 8) | ((c & 0xff) << 16) | (d << 24);
}

// ---- fused conversion: x int32->int8 and w fp32->int8, one launch -----------
// one thread per 4 elements: 16B coalesced load, 4B coalesced packed store.
// blocks [0, XB): x;  blocks [XB, XB+WB): w.
#define XB 32768
#define WB 16384
__global__ void __launch_bounds__(256) cvt_kernel(const int4* __restrict__ x,
                                                  const float4* __restrict__ w,
                                                  int* __restrict__ ox,
                                                  int* __restrict__ ow) {
  int b = blockIdx.x;
  if (b < XB) {
    size_t i = (size_t)b * 256 + threadIdx.x;
    int4 a = x[i];
    ox[i] = pack4i(a.x, a.y, a.z, a.w);
  } else {
    size_t i = (size_t)(b - XB) * 256 + threadIdx.x;
    float4 a = w[i];
    ow[i] = pack4i(__float2int_rn(a.x), __float2int_rn(a.y),
                   __float2int_rn(a.z), __float2int_rn(a.w));
  }
}

// ---- i8 MFMA GEMM: C[m,n] = sum_k A[m,k]*B[n,k]  (both row-major [rows][K]) -
// block tile 128x128, BK=64; 4 waves in 2x2, each wave 64x64 via 4x4 tiles of
// mfma_i32_16x16x64_i8.
// LDS layout XOR-swizzled: 16B chunk (row, kc) stored at idx row*4 + (kc ^
// ((row>>1)&3)).  Swizzle applied on the GLOBAL source address during staging
// (global_load_lds LDS dest is fixed lane-contiguous); fragment ds_read_b128
// then hits each 4-bank group exactly 2x per 16-lane quarter (2-way = free).
__global__ void __launch_bounds__(256) gemm_i8_kernel(
    const int8_t* __restrict__ A8, const int8_t* __restrict__ B8,
    const float* __restrict__ bias, const float* __restrict__ alpha_p,
    int* __restrict__ out) {
  __shared__ int8_t As[BM * BK];  // 8 KB
  __shared__ int8_t Bs[BN * BK];  // 8 KB

  const int t = threadIdx.x;
  const int wave = t >> 6;
  const int lane = t & 63;
  const int quad = lane >> 4;   // 0..3
  const int l15 = lane & 15;
  const int wm = wave >> 1;     // 0..1
  const int wn = wave & 1;      // 0..1

  const int bn = blockIdx.x;    // 0..31
  const int bm = blockIdx.y;    // 0..63

  // staging: thread t owns LDS chunks idx=t and idx=t+256 (lane-contiguous).
  // LDS idx -> global chunk: row = idx>>2, kc = (idx&3) ^ ((row>>1)&3).
  // second chunk's row = rowS+64: swizzle bits unchanged (64>>1 = 32 ≡ 0 mod 4).
  const int rowS = t >> 2;                         // 0..63
  const int colS = ((t & 3) ^ ((rowS >> 1) & 3)) * 16;
  const int8_t* ag0 = A8 + (size_t)(bm * BM + rowS) * IN_F + colS;
  const int8_t* ag1 = ag0 + (size_t)64 * IN_F;
  const int8_t* bg0 = B8 + (size_t)(bn * BN + rowS) * IN_F + colS;
  const int8_t* bg1 = bg0 + (size_t)64 * IN_F;
  int8_t* la0 = As + t * 16;
  int8_t* la1 = As + t * 16 + 4096;
  int8_t* lb0 = Bs + t * 16;
  int8_t* lb1 = Bs + t * 16 + 4096;

  // fragment read: row = (wm*64 + l15) + 16*mi; (row>>1)&3 == (l15>>1)&3 for
  // all mi/wm (offsets are multiples of 16 -> bits unchanged).
  const int32x4* As4 = (const int32x4*)As;
  const int32x4* Bs4 = (const int32x4*)Bs;
  const int swz = (l15 >> 1) & 3;
  const int aoff = (wm * 64 + l15) * 4 + (quad ^ swz);
  const int boff = (wn * 64 + l15) * 4 + (quad ^ swz);

  int32x4 acc[4][4] = {};

  for (int k0 = 0; k0 < IN_F; k0 += BK) {
    GLOAD_LDS16(ag0 + k0, la0);
    GLOAD_LDS16(ag1 + k0, la1);
    GLOAD_LDS16(bg0 + k0, lb0);
    GLOAD_LDS16(bg1 + k0, lb1);
    __syncthreads();

    int32x4 af[4], bf[4];
#pragma unroll
    for (int i = 0; i < 4; ++i) af[i] = As4[aoff + i * 64];  // +16 rows
#pragma unroll
    for (int i = 0; i < 4; ++i) bf[i] = Bs4[boff + i * 64];
#pragma unroll
    for (int mi = 0; mi < 4; ++mi)
#pragma unroll
      for (int ni = 0; ni < 4; ++ni)
        acc[mi][ni] = __builtin_amdgcn_mfma_i32_16x16x64_i8(af[mi], bf[ni],
                                                            acc[mi][ni], 0, 0, 0);
    __syncthreads();
  }

  // epilogue: C/D layout col = lane&15, row = quad*4 + reg (dtype-independent)
  const float alpha = *alpha_p;
  const int colg = bn * BN + wn * 64 + l15;
  const int rowg = bm * BM + wm * 64 + quad * 4;
#pragma unroll
  for (int mi = 0; mi < 4; ++mi) {
#pragma unroll
    for (int ni = 0; ni < 4; ++ni) {
      const int col = colg + ni * 16;
      const float bv = bias[col];
#pragma unroll
      for (int r = 0; r < 4; ++r) {
        const int row = rowg + mi * 16 + r;
        float v = rintf((float)acc[mi][ni][r] * alpha + bv);
        v = fminf(fmaxf(v, -128.f), 127.f);
        out[(size_t)row * OUT_F + col] = (int)v;
      }
    }
  }
}

extern "C" void kernel_launch(void* const* d_in, const int* in_sizes, int n_in,
                              void* d_out, int out_size, void* d_ws, size_t ws_size,
                              hipStream_t stream) {
  const int*   x     = (const int*)d_in[0];    // [8192, 4096] int8-valued
  const float* w     = (const float*)d_in[1];  // [4096, 4096] int8-valued
  const float* bias  = (const float*)d_in[2];  // [4096]
  const float* alpha = (const float*)d_in[3];  // scalar
  int* out = (int*)d_out;                      // [8192, 4096] int32 (int8 values)

  int8_t* x8 = (int8_t*)d_ws;                        // 33,554,432 B
  int8_t* w8 = x8 + (size_t)ROWS * IN_F;             // 16,777,216 B (total 48 MB)

  cvt_kernel<<<XB + WB, 256, 0, stream>>>((const int4*)x, (const float4*)w,
                                          (int*)x8, (int*)w8);

  dim3 grid(OUT_F / BN, ROWS / BM);  // (32, 64)
  gemm_i8_kernel<<<grid, 256, 0, stream>>>(x8, w8, bias, alpha, out);
}

// Round 5
// 400.012 us; speedup vs baseline: 1.0500x; 1.0295x over previous
//
#include <hip/hip_runtime.h>
#include <stdint.h>

typedef int int32x4 __attribute__((ext_vector_type(4)));

#define IN_F   4096
#define OUT_F  4096
#define ROWS   8192   /* 4 * 2048 */

#define BM 128
#define BN 128
#define BK 128

// async global->LDS, 16B per lane; LDS side must be lane-contiguous (m104/m108)
#define GLOAD_LDS16(g, l)                                                      \
  __builtin_amdgcn_global_load_lds(                                            \
      (const __attribute__((address_space(1))) void*)(g),                      \
      (__attribute__((address_space(3))) void*)(l), 16, 0, 0)

__device__ __forceinline__ int pack4i(int a, int b, int c, int d) {
  return (a & 0xff) | ((b & 0xff) << 8) | ((c & 0xff) << 16) | (d << 24);
}

// ---- fused conversion: x int32->int8 and w fp32->int8, one launch -----------
#define XB 32768
#define WB 16384
__global__ void __launch_bounds__(256) cvt_kernel(const int4* __restrict__ x,
                                                  const float4* __restrict__ w,
                                                  int* __restrict__ ox,
                                                  int* __restrict__ ow) {
  int b = blockIdx.x;
  if (b < XB) {
    size_t i = (size_t)b * 256 + threadIdx.x;
    int4 a = x[i];
    ox[i] = pack4i(a.x, a.y, a.z, a.w);
  } else {
    size_t i = (size_t)(b - XB) * 256 + threadIdx.x;
    float4 a = w[i];
    ow[i] = pack4i(__float2int_rn(a.x), __float2int_rn(a.y),
                   __float2int_rn(a.z), __float2int_rn(a.w));
  }
}

// ---- i8 MFMA GEMM: C[m,n] = sum_k A[m,k]*B[n,k]  (both row-major [rows][K]) -
// block tile 128x128, BK=128 (32 KB LDS total -> no occupancy cliff at i8,
// unlike bf16/m132); 4 waves in 2x2, each wave 64x64 via 4x4 tiles of
// mfma_i32_16x16x64_i8, two K=64 substeps per barrier (halves barrier-drain
// count vs BK=64 -- the measured plateau cause).
// LDS XOR-swizzle: 16B chunk (row, kc), kc in [0,8), stored at idx
// row*8 + (kc ^ (row&7)); applied on the GLOBAL source address during staging
// (global_load_lds LDS dest is fixed lane-contiguous).  Fragment ds_read_b128
// then hits each 16B slot exactly 2x per 16-lane quarter (2-way = free).
__global__ void __launch_bounds__(256) gemm_i8_kernel(
    const int8_t* __restrict__ A8, const int8_t* __restrict__ B8,
    const float* __restrict__ bias, const float* __restrict__ alpha_p,
    int* __restrict__ out) {
  __shared__ int8_t As[BM * BK];  // 16 KB
  __shared__ int8_t Bs[BN * BK];  // 16 KB

  const int t = threadIdx.x;
  const int wave = t >> 6;
  const int lane = t & 63;
  const int quad = lane >> 4;   // 0..3
  const int l15 = lane & 15;
  const int wm = wave >> 1;     // 0..1
  const int wn = wave & 1;      // 0..1

  const int bn = blockIdx.x;    // 0..31
  const int bm = blockIdx.y;    // 0..63

  // staging: 1024 chunks of 16B per matrix; thread t owns chunks t+256j,
  // j=0..3 (rows rowS+32j; 32 is mult of 8 -> swizzle bits unchanged).
  const int rowS = t >> 3;                          // 0..31
  const int colS = ((t & 7) ^ (rowS & 7)) * 16;
  const int8_t* ag = A8 + (size_t)(bm * BM + rowS) * IN_F + colS;
  const int8_t* bg = B8 + (size_t)(bn * BN + rowS) * IN_F + colS;
  int8_t* la = As + t * 16;
  int8_t* lb = Bs + t * 16;

  // fragment read idx (16B units): (row)*8 + ((kk*4+quad) ^ (row&7)),
  // row = wm*64 + l15 + mi*16; row&7 == l15&7 for all mi/wm.
  const int32x4* As4 = (const int32x4*)As;
  const int32x4* Bs4 = (const int32x4*)Bs;
  const int swz = l15 & 7;
  const int abase = (wm * 64 + l15) * 8;
  const int bbase = (wn * 64 + l15) * 8;

  int32x4 acc[4][4] = {};

  for (int k0 = 0; k0 < IN_F; k0 += BK) {
#pragma unroll
    for (int j = 0; j < 4; ++j) {
      GLOAD_LDS16(ag + k0 + (size_t)(32 * j) * IN_F, la + 4096 * j);
      GLOAD_LDS16(bg + k0 + (size_t)(32 * j) * IN_F, lb + 4096 * j);
    }
    __syncthreads();

#pragma unroll
    for (int kk = 0; kk < 2; ++kk) {
      const int ksw = (kk * 4 + quad) ^ swz;
      int32x4 af[4], bf[4];
#pragma unroll
      for (int i = 0; i < 4; ++i) af[i] = As4[abase + i * 128 + ksw];
#pragma unroll
      for (int i = 0; i < 4; ++i) bf[i] = Bs4[bbase + i * 128 + ksw];
#pragma unroll
      for (int mi = 0; mi < 4; ++mi)
#pragma unroll
        for (int ni = 0; ni < 4; ++ni)
          acc[mi][ni] = __builtin_amdgcn_mfma_i32_16x16x64_i8(
              af[mi], bf[ni], acc[mi][ni], 0, 0, 0);
    }
    __syncthreads();
  }

  // epilogue: C/D layout col = lane&15, row = quad*4 + reg (dtype-independent)
  const float alpha = *alpha_p;
  const int colg = bn * BN + wn * 64 + l15;
  const int rowg = bm * BM + wm * 64 + quad * 4;
#pragma unroll
  for (int mi = 0; mi < 4; ++mi) {
#pragma unroll
    for (int ni = 0; ni < 4; ++ni) {
      const int col = colg + ni * 16;
      const float bv = bias[col];
#pragma unroll
      for (int r = 0; r < 4; ++r) {
        const int row = rowg + mi * 16 + r;
        float v = rintf((float)acc[mi][ni][r] * alpha + bv);
        v = fminf(fmaxf(v, -128.f), 127.f);
        out[(size_t)row * OUT_F + col] = (int)v;
      }
    }
  }
}

extern "C" void kernel_launch(void* const* d_in, const int* in_sizes, int n_in,
                              void* d_out, int out_size, void* d_ws, size_t ws_size,
                              hipStream_t stream) {
  const int*   x     = (const int*)d_in[0];    // [8192, 4096] int8-valued
  const float* w     = (const float*)d_in[1];  // [4096, 4096] int8-valued
  const float* bias  = (const float*)d_in[2];  // [4096]
  const float* alpha = (const float*)d_in[3];  // scalar
  int* out = (int*)d_out;                      // [8192, 4096] int32 (int8 values)

  int8_t* x8 = (int8_t*)d_ws;                        // 33,554,432 B
  int8_t* w8 = x8 + (size_t)ROWS * IN_F;             // 16,777,216 B (total 48 MB)

  cvt_kernel<<<XB + WB, 256, 0, stream>>>((const int4*)x, (const float4*)w,
                                          (int*)x8, (int*)w8);

  dim3 grid(OUT_F / BN, ROWS / BM);  // (32, 64)
  gemm_i8_kernel<<<grid, 256, 0, stream>>>(x8, w8, bias, alpha, out);
}

// Round 6
// 394.857 us; speedup vs baseline: 1.0637x; 1.0131x over previous
//
#include <hip/hip_runtime.h>
#include <stdint.h>

typedef int int32x4  __attribute__((ext_vector_type(4)));
typedef int int32x16 __attribute__((ext_vector_type(16)));

#define IN_F   4096
#define OUT_F  4096
#define ROWS   8192   /* 4 * 2048 */

#define BM 128
#define BN 128
#define BK 128

// async global->LDS, 16B per lane; LDS side must be lane-contiguous (m104/m108)
#define GLOAD_LDS16(g, l)                                                      \
  __builtin_amdgcn_global_load_lds(                                            \
      (const __attribute__((address_space(1))) void*)(g),                      \
      (__attribute__((address_space(3))) void*)(l), 16, 0, 0)

__device__ __forceinline__ int pack4i(int a, int b, int c, int d) {
  return (a & 0xff) | ((b & 0xff) << 8) | ((c & 0xff) << 16) | (d << 24);
}

// ---- fused conversion: x int32->int8 and w fp32->int8, one launch -----------
#define XB 32768
#define WB 16384
__global__ void __launch_bounds__(256) cvt_kernel(const int4* __restrict__ x,
                                                  const float4* __restrict__ w,
                                                  int* __restrict__ ox,
                                                  int* __restrict__ ow) {
  int b = blockIdx.x;
  if (b < XB) {
    size_t i = (size_t)b * 256 + threadIdx.x;
    int4 a = x[i];
    ox[i] = pack4i(a.x, a.y, a.z, a.w);
  } else {
    size_t i = (size_t)(b - XB) * 256 + threadIdx.x;
    float4 a = w[i];
    ow[i] = pack4i(__float2int_rn(a.x), __float2int_rn(a.y),
                   __float2int_rn(a.z), __float2int_rn(a.w));
  }
}

// ---- i8 MFMA GEMM: C[m,n] = sum_k A[m,k]*B[n,k]  (both row-major [rows][K]) -
// block tile 128x128, BK=128 (32 KB LDS); 4 waves in 2x2, each wave 64x64 via
// 2x2 tiles of mfma_i32_32x32x32_i8 (4404 TOPS ubench vs 3944 for 16x16x64;
// half the MFMA instruction count at identical LDS traffic).
// A-operand layout (generalized from verified 16x16x64): m = lane&31,
// k = (lane>>5)*16 + j  (lane's 16 contiguous bytes).  C/D: col = lane&31,
// row = (reg&3) + 8*(reg>>2) + 4*(lane>>5)  [m74/m101, dtype-independent].
// LDS XOR-swizzle: 16B chunk (row, kc), kc in [0,8), stored at idx
// row*8 + (kc ^ (row&7)); applied on the GLOBAL source address during staging
// (global_load_lds LDS dest is fixed lane-contiguous).
__global__ void __launch_bounds__(256) gemm_i8_kernel(
    const int8_t* __restrict__ A8, const int8_t* __restrict__ B8,
    const float* __restrict__ bias, const float* __restrict__ alpha_p,
    int* __restrict__ out) {
  __shared__ int8_t As[BM * BK];  // 16 KB
  __shared__ int8_t Bs[BN * BK];  // 16 KB

  const int t = threadIdx.x;
  const int wave = t >> 6;
  const int lane = t & 63;
  const int l31 = lane & 31;
  const int hi  = lane >> 5;    // 0..1
  const int wm = wave >> 1;     // 0..1
  const int wn = wave & 1;      // 0..1

  const int bn = blockIdx.x;    // 0..31
  const int bm = blockIdx.y;    // 0..63

  // staging: 1024 chunks of 16B per matrix; thread t owns chunks t+256j,
  // j=0..3 (rows rowS+32j; 32 is mult of 8 -> swizzle bits unchanged).
  const int rowS = t >> 3;                          // 0..31
  const int colS = ((t & 7) ^ (rowS & 7)) * 16;
  const int8_t* ag = A8 + (size_t)(bm * BM + rowS) * IN_F + colS;
  const int8_t* bg = B8 + (size_t)(bn * BN + rowS) * IN_F + colS;
  int8_t* la = As + t * 16;
  int8_t* lb = Bs + t * 16;

  // fragment read idx (16B units): row*8 + (kc ^ (row&7)),
  // row = wm*64 + mi*32 + l31 -> row&7 == l31&7 (offsets are mult of 32);
  // kc = ks*2 + hi.
  const int32x4* As4 = (const int32x4*)As;
  const int32x4* Bs4 = (const int32x4*)Bs;
  const int swz = l31 & 7;
  const int arow0 = (wm * 64 + l31) * 8;   // +mi*256
  const int brow0 = (wn * 64 + l31) * 8;   // +ni*256

  int32x16 acc[2][2] = {};

  for (int k0 = 0; k0 < IN_F; k0 += BK) {
#pragma unroll
    for (int j = 0; j < 4; ++j) {
      GLOAD_LDS16(ag + k0 + (size_t)(32 * j) * IN_F, la + 4096 * j);
      GLOAD_LDS16(bg + k0 + (size_t)(32 * j) * IN_F, lb + 4096 * j);
    }
    __syncthreads();

#pragma unroll
    for (int ks = 0; ks < 4; ++ks) {
      const int ksw = (ks * 2 + hi) ^ swz;
      int32x4 af[2], bf[2];
#pragma unroll
      for (int i = 0; i < 2; ++i) af[i] = As4[arow0 + i * 256 + ksw];
#pragma unroll
      for (int i = 0; i < 2; ++i) bf[i] = Bs4[brow0 + i * 256 + ksw];
#pragma unroll
      for (int mi = 0; mi < 2; ++mi)
#pragma unroll
        for (int ni = 0; ni < 2; ++ni)
          acc[mi][ni] = __builtin_amdgcn_mfma_i32_32x32x32_i8(
              af[mi], bf[ni], acc[mi][ni], 0, 0, 0);
    }
    __syncthreads();
  }

  // epilogue: C/D col = lane&31, row = (reg&3) + 8*(reg>>2) + 4*hi
  const float alpha = *alpha_p;
#pragma unroll
  for (int mi = 0; mi < 2; ++mi) {
    const int rowt = bm * BM + wm * 64 + mi * 32 + hi * 4;
#pragma unroll
    for (int ni = 0; ni < 2; ++ni) {
      const int col = bn * BN + wn * 64 + ni * 32 + l31;
      const float bv = bias[col];
#pragma unroll
      for (int r = 0; r < 16; ++r) {
        const int row = rowt + (r & 3) + 8 * (r >> 2);
        float v = rintf((float)acc[mi][ni][r] * alpha + bv);
        v = fminf(fmaxf(v, -128.f), 127.f);
        out[(size_t)row * OUT_F + col] = (int)v;
      }
    }
  }
}

extern "C" void kernel_launch(void* const* d_in, const int* in_sizes, int n_in,
                              void* d_out, int out_size, void* d_ws, size_t ws_size,
                              hipStream_t stream) {
  const int*   x     = (const int*)d_in[0];    // [8192, 4096] int8-valued
  const float* w     = (const float*)d_in[1];  // [4096, 4096] int8-valued
  const float* bias  = (const float*)d_in[2];  // [4096]
  const float* alpha = (const float*)d_in[3];  // scalar
  int* out = (int*)d_out;                      // [8192, 4096] int32 (int8 values)

  int8_t* x8 = (int8_t*)d_ws;                        // 33,554,432 B
  int8_t* w8 = x8 + (size_t)ROWS * IN_F;             // 16,777,216 B (total 48 MB)

  cvt_kernel<<<XB + WB, 256, 0, stream>>>((const int4*)x, (const float4*)w,
                                          (int*)x8, (int*)w8);

  dim3 grid(OUT_F / BN, ROWS / BM);  // (32, 64)
  gemm_i8_kernel<<<grid, 256, 0, stream>>>(x8, w8, bias, alpha, out);
}